// Round 1
// baseline (698.630 us; speedup 1.0000x reference)
//
#include <hip/hip_runtime.h>
#include <hip/hip_bf16.h>

#define N_NODES 325
#define C_DIM   64
#define BATCH   64
#define SEQ     12
#define NT      (N_NODES * SEQ)   // 3900
#define NT4     (NT / 4)          // 975
#define G_TOTAL (BATCH * C_DIM)   // 4096

// ---- bf16 helpers (bit-level, no type dependencies) ----
static __device__ __forceinline__ unsigned short f2bf(float f) {
    unsigned int u = __float_as_uint(f);
    unsigned int r = (u + 0x7fffu + ((u >> 16) & 1u)) >> 16;  // RNE
    return (unsigned short)r;
}
static __device__ __forceinline__ float bf2f(unsigned short u) {
    return __uint_as_float(((unsigned int)u) << 16);
}

// ---- Kernel 0a: build CSR of L = I - D^{-1/2} A D^{-1/2} ----
__global__ void build_csr(const float* __restrict__ adj,
                          int* __restrict__ rowptr,
                          int* __restrict__ col,
                          float* __restrict__ val) {
    __shared__ float dis[N_NODES];
    __shared__ int   cnt[N_NODES];
    __shared__ int   rp[N_NODES + 1];
    const int tid = threadIdx.x;
    for (int i = tid; i < N_NODES; i += blockDim.x) {
        const float* row = adj + (size_t)i * N_NODES;
        float d = 0.f; int c = 0;
        for (int j = 0; j < N_NODES; ++j) {
            float a = row[j];
            d += a;
            c += (a != 0.f) ? 1 : 0;
        }
        dis[i] = (d > 0.f) ? rsqrtf(d) : 0.f;
        cnt[i] = c;
    }
    __syncthreads();
    if (tid == 0) {
        int acc = 0;
        rp[0] = 0;
        for (int i = 0; i < N_NODES; ++i) { acc += cnt[i]; rp[i + 1] = acc; }
    }
    __syncthreads();
    for (int i = tid; i <= N_NODES; i += blockDim.x) rowptr[i] = rp[i];
    for (int i = tid; i < N_NODES; i += blockDim.x) {
        const float* row = adj + (size_t)i * N_NODES;
        int p = rp[i];
        float di = dis[i];
        for (int j = 0; j < N_NODES; ++j) {
            float a = row[j];
            if (a != 0.f) {
                float v = ((i == j) ? 1.f : 0.f) - di * a * dis[j];
                col[p] = j;
                val[p] = v;
                ++p;
            }
        }
    }
}

// ---- Kernel 0b: fold weights: Wcat[c][0][d]=W0-W2, [1]=W1, [2]=2*W2 ----
__global__ void build_wcat(const float* __restrict__ W, float* __restrict__ wcat) {
    int idx = blockIdx.x * blockDim.x + threadIdx.x;
    if (idx >= 3 * C_DIM * C_DIM) return;
    int c = idx / (3 * C_DIM);
    int r = idx - c * 3 * C_DIM;
    int k = r / C_DIM;
    int d = r - k * C_DIM;
    int cd = c * C_DIM + d;
    float v;
    if (k == 0)      v = W[cd] - W[2 * C_DIM * C_DIM + cd];
    else if (k == 1) v = W[C_DIM * C_DIM + cd];
    else             v = 2.f * W[2 * C_DIM * C_DIM + cd];
    wcat[idx] = v;
}

// ---- Phase A: per g=(b,c) slice, Y = L X ; Z = L Y (sparse, LDS-staged) ----
__global__ __launch_bounds__(256) void cheb_apply(
        const float* __restrict__ x,
        const int* __restrict__ rowptr,
        const int* __restrict__ col,
        const float* __restrict__ val,
        unsigned short* __restrict__ Yg,
        unsigned short* __restrict__ Zg) {
    __shared__ float Xl[NT];
    __shared__ float Yl[NT];
    const int g = blockIdx.x;
    const int tid = threadIdx.x;

    const float4* Xg4 = (const float4*)(x + (size_t)g * NT);
    float4* Xl4 = (float4*)Xl;
    for (int k = tid; k < NT4; k += 256) Xl4[k] = Xg4[k];
    __syncthreads();

    // Y = L X
    for (int it = tid; it < NT4; it += 256) {
        int n = it / 3;
        int q = it - n * 3;
        int e0 = rowptr[n], e1 = rowptr[n + 1];
        float4 acc = make_float4(0.f, 0.f, 0.f, 0.f);
        for (int e = e0; e < e1; ++e) {
            float v = val[e];
            const float4 xx = *(const float4*)(Xl + col[e] * SEQ + q * 4);
            acc.x += v * xx.x; acc.y += v * xx.y;
            acc.z += v * xx.z; acc.w += v * xx.w;
        }
        int base = n * SEQ + q * 4;
        *(float4*)(Yl + base) = acc;
        ushort4 u;
        u.x = f2bf(acc.x); u.y = f2bf(acc.y); u.z = f2bf(acc.z); u.w = f2bf(acc.w);
        *(ushort4*)(Yg + (size_t)g * NT + base) = u;
    }
    __syncthreads();

    // Z = L Y
    for (int it = tid; it < NT4; it += 256) {
        int n = it / 3;
        int q = it - n * 3;
        int e0 = rowptr[n], e1 = rowptr[n + 1];
        float4 acc = make_float4(0.f, 0.f, 0.f, 0.f);
        for (int e = e0; e < e1; ++e) {
            float v = val[e];
            const float4 yy = *(const float4*)(Yl + col[e] * SEQ + q * 4);
            acc.x += v * yy.x; acc.y += v * yy.y;
            acc.z += v * yy.z; acc.w += v * yy.w;
        }
        int base = n * SEQ + q * 4;
        ushort4 u;
        u.x = f2bf(acc.x); u.y = f2bf(acc.y); u.z = f2bf(acc.z); u.w = f2bf(acc.w);
        *(ushort4*)(Zg + (size_t)g * NT + base) = u;
    }
}

// ---- Phase B: out[b,d,nt] = sum_c X*W0' + Y*W1 + Z*W2' + bias ----
__global__ __launch_bounds__(256) void mix_out(
        const float* __restrict__ x,
        const unsigned short* __restrict__ Yg,
        const unsigned short* __restrict__ Zg,
        const float* __restrict__ wcat,
        const float* __restrict__ bias,
        float* __restrict__ out) {
    __shared__ float Wl[3 * C_DIM * C_DIM];   // 12288 floats = 48 KB
    __shared__ float bl[C_DIM];
    const int tid = threadIdx.x;
    for (int i = tid; i < 3 * C_DIM * C_DIM; i += 256) Wl[i] = wcat[i];
    if (tid < C_DIM) bl[tid] = bias[tid];
    __syncthreads();

    const int b = blockIdx.y;
    const int nt = blockIdx.x * 256 + tid;
    if (nt >= NT) return;

    const float* Xb = x + (size_t)b * (C_DIM * NT) + nt;
    const unsigned short* Yb = Yg + (size_t)b * (C_DIM * NT) + nt;
    const unsigned short* Zb = Zg + (size_t)b * (C_DIM * NT) + nt;

    float4 acc[16];
    #pragma unroll
    for (int i = 0; i < 16; ++i) acc[i] = make_float4(0.f, 0.f, 0.f, 0.f);

    for (int c = 0; c < C_DIM; ++c) {
        float xv = Xb[(size_t)c * NT];
        float yv = bf2f(Yb[(size_t)c * NT]);
        float zv = bf2f(Zb[(size_t)c * NT]);
        const float4* w = (const float4*)(Wl + c * 192);
        #pragma unroll
        for (int dq = 0; dq < 16; ++dq) {
            float4 w0 = w[dq];
            float4 w1 = w[16 + dq];
            float4 w2 = w[32 + dq];
            acc[dq].x += xv * w0.x + yv * w1.x + zv * w2.x;
            acc[dq].y += xv * w0.y + yv * w1.y + zv * w2.y;
            acc[dq].z += xv * w0.z + yv * w1.z + zv * w2.z;
            acc[dq].w += xv * w0.w + yv * w1.w + zv * w2.w;
        }
    }

    float* ob = out + (size_t)b * (C_DIM * NT) + nt;
    #pragma unroll
    for (int dq = 0; dq < 16; ++dq) {
        ob[(size_t)(4 * dq + 0) * NT] = acc[dq].x + bl[4 * dq + 0];
        ob[(size_t)(4 * dq + 1) * NT] = acc[dq].y + bl[4 * dq + 1];
        ob[(size_t)(4 * dq + 2) * NT] = acc[dq].z + bl[4 * dq + 2];
        ob[(size_t)(4 * dq + 3) * NT] = acc[dq].w + bl[4 * dq + 3];
    }
}

extern "C" void kernel_launch(void* const* d_in, const int* in_sizes, int n_in,
                              void* d_out, int out_size, void* d_ws, size_t ws_size,
                              hipStream_t stream) {
    const float* x   = (const float*)d_in[0];
    const float* adj = (const float*)d_in[1];
    const float* W   = (const float*)d_in[2];
    const float* b   = (const float*)d_in[3];
    float* out = (float*)d_out;

    char* ws = (char*)d_ws;
    // layout (bytes):
    //   0        : wcat   (12288 f32 = 49152)
    //   49152    : rowptr (326 i32, padded to 1312)
    //   50464    : col    (105950 i32, padded to 423808)
    //   474272   : val    (105950 f32, padded to 423808)
    //   898304   : Y      (15974400 bf16 = 31948800)
    //   32847104 : Z      (15974400 bf16 = 31948800)
    //   total ~64.8 MB
    float* wcat          = (float*)(ws + 0);
    int*   rowptr        = (int*)  (ws + 49152);
    int*   colA          = (int*)  (ws + 50464);
    float* valA          = (float*)(ws + 474272);
    unsigned short* Yg   = (unsigned short*)(ws + 898304);
    unsigned short* Zg   = (unsigned short*)(ws + 32847104);

    build_csr<<<1, 512, 0, stream>>>(adj, rowptr, colA, valA);
    build_wcat<<<48, 256, 0, stream>>>(W, wcat);
    cheb_apply<<<G_TOTAL, 256, 0, stream>>>(x, rowptr, colA, valA, Yg, Zg);
    mix_out<<<dim3((NT + 255) / 256, BATCH), 256, 0, stream>>>(x, Yg, Zg, wcat, b, out);
}

// Round 2
// 446.810 us; speedup vs baseline: 1.5636x; 1.5636x over previous
//
#include <hip/hip_runtime.h>
#include <hip/hip_bf16.h>

#define N_NODES 325
#define C_DIM   64
#define BATCH   64
#define SEQ     12
#define NT      (N_NODES * SEQ)   // 3900
#define G_TOTAL (BATCH * C_DIM)   // 4096

typedef __attribute__((ext_vector_type(8))) short short8;
typedef __attribute__((ext_vector_type(4))) float floatx4;

// ---- bf16 helpers ----
static __device__ __forceinline__ unsigned short f2bf(float f) {
    unsigned int u = __float_as_uint(f);
    unsigned int r = (u + 0x7fffu + ((u >> 16) & 1u)) >> 16;  // RNE
    return (unsigned short)r;
}

// XOR swizzle for [row][192k] bf16 LDS images (stride 384 B): spreads the
// 16-B k-chunks across banks using both low and mid row bits.
static __device__ __forceinline__ int swz(int n) {
    return ((n & 7) ^ ((n >> 3) & 7)) << 4;
}

// ---- Kernel 0a: CSR of L = I - D^{-1/2} A D^{-1/2}; edges = {col*384, val bits} ----
__global__ void build_csr(const float* __restrict__ adj,
                          int* __restrict__ rowptr,
                          int2* __restrict__ edges) {
    __shared__ float dis[N_NODES];
    __shared__ int   cnt[N_NODES];
    __shared__ int   rp[N_NODES + 1];
    const int tid = threadIdx.x;
    for (int i = tid; i < N_NODES; i += blockDim.x) {
        const float* row = adj + (size_t)i * N_NODES;
        float d = 0.f; int c = 0;
        for (int j = 0; j < N_NODES; ++j) {
            float a = row[j];
            d += a;
            c += (a != 0.f) ? 1 : 0;
        }
        dis[i] = (d > 0.f) ? rsqrtf(d) : 0.f;
        cnt[i] = c;
    }
    __syncthreads();
    if (tid == 0) {
        int acc = 0;
        rp[0] = 0;
        for (int i = 0; i < N_NODES; ++i) { acc += cnt[i]; rp[i + 1] = acc; }
    }
    __syncthreads();
    for (int i = tid; i <= N_NODES; i += blockDim.x) rowptr[i] = rp[i];
    for (int i = tid; i < N_NODES; i += blockDim.x) {
        const float* row = adj + (size_t)i * N_NODES;
        int p = rp[i];
        float di = dis[i];
        for (int j = 0; j < N_NODES; ++j) {
            float a = row[j];
            if (a != 0.f) {
                float v = ((i == j) ? 1.f : 0.f) - di * a * dis[j];
                int2 e;
                e.x = j * 384;              // byte offset of row j in spmm LDS
                e.y = __float_as_int(v);
                edges[p] = e;
                ++p;
            }
        }
    }
}

// ---- Kernel 0b: folded weights as swizzled bf16 LDS image A[d][k], k=kind*64+c ----
__global__ void build_wswz(const float* __restrict__ W, unsigned short* __restrict__ wswz) {
    int idx = blockIdx.x * 256 + threadIdx.x;
    if (idx >= 64 * 192) return;
    int d = idx / 192, k = idx - d * 192;
    int kind = k >> 6, c = k & 63;
    float wv = W[kind * 4096 + c * 64 + d];
    float w;
    if (kind == 0)      w = wv - W[2 * 4096 + c * 64 + d];
    else if (kind == 1) w = wv;
    else                w = 2.f * wv;
    int byte = d * 384 + ((2 * k) ^ swz(d));
    wswz[byte >> 1] = f2bf(w);
}

// ---- Phase A: dst = L * src for 16 slices per block.
// LDS holds src slices bf16 as S[j=node][ct=gl*12+t] (325 x 192 shorts).
// One wave processes one row n for all 192 columns: CSR access is wave-uniform
// (scalarized via readfirstlane), LDS reads are 48 consecutive b64 lanes.
template<int BF16SRC>
__global__ __launch_bounds__(512) void spmm16(
        const void* __restrict__ srcv,
        const int* __restrict__ rowptr,
        const int2* __restrict__ edges,
        unsigned short* __restrict__ dst) {
    __shared__ unsigned short S[325 * 192];   // 124800 B
    const int tid = threadIdx.x;
    const int g0 = blockIdx.x * 16;

    if (BF16SRC) {
        const unsigned short* src = (const unsigned short*)srcv;
        for (int i = tid; i < 15600; i += 512) {
            int gl = i / 975, kk = i - gl * 975;
            int flat = kk * 4;
            int j = flat / 12, t = flat - j * 12;
            ushort4 v = *(const ushort4*)(src + (size_t)(g0 + gl) * NT + flat);
            *(ushort4*)(S + j * 192 + gl * 12 + t) = v;
        }
    } else {
        const float* src = (const float*)srcv;
        for (int i = tid; i < 15600; i += 512) {
            int gl = i / 975, kk = i - gl * 975;
            int flat = kk * 4;
            int j = flat / 12, t = flat - j * 12;
            float4 v = *(const float4*)(src + (size_t)(g0 + gl) * NT + flat);
            ushort4 u;
            u.x = f2bf(v.x); u.y = f2bf(v.y); u.z = f2bf(v.z); u.w = f2bf(v.w);
            *(ushort4*)(S + j * 192 + gl * 12 + t) = u;
        }
    }
    __syncthreads();

    const int wid = __builtin_amdgcn_readfirstlane(tid >> 6);  // force wave-uniform
    const int lane = tid & 63;
    if (lane < 48) {
        const int gl = lane / 3;             // 4 cols per lane -> slice index
        const int tq = lane - gl * 3;        // t-quad within slice
        for (int n = wid; n < N_NODES; n += 8) {
            const int e0 = rowptr[n], e1 = rowptr[n + 1];
            float a0 = 0.f, a1 = 0.f, a2 = 0.f, a3 = 0.f;
            for (int e = e0; e < e1; ++e) {
                int2 ed = edges[e];
                float v = __int_as_float(ed.y);
                const unsigned int* p =
                    (const unsigned int*)((const char*)S + ed.x + lane * 8);
                unsigned int lo = p[0], hi = p[1];
                a0 = fmaf(v, __uint_as_float(lo << 16), a0);
                a1 = fmaf(v, __uint_as_float(lo & 0xffff0000u), a1);
                a2 = fmaf(v, __uint_as_float(hi << 16), a2);
                a3 = fmaf(v, __uint_as_float(hi & 0xffff0000u), a3);
            }
            ushort4 u;
            u.x = f2bf(a0); u.y = f2bf(a1); u.z = f2bf(a2); u.w = f2bf(a3);
            *(ushort4*)(dst + (size_t)(g0 + gl) * NT + n * 12 + tq * 4) = u;
        }
    }
}

// ---- Phase B: out[b,d,nt] = sum_k A[d,k] * B[k,nt] + bias[d], MFMA 16x16x32 bf16.
// A = wswz (64x192, swizzled image). B tile = 96 columns of [X(fp32->bf16); Y; Z],
// staged into swizzled [n][k] LDS image. 4 waves, each computes a 16x96 strip.
__global__ __launch_bounds__(256) void mix_mfma(
        const float* __restrict__ x,
        const unsigned short* __restrict__ Yg,
        const unsigned short* __restrict__ Zg,
        const unsigned short* __restrict__ wswz,
        const float* __restrict__ bias,
        float* __restrict__ out) {
    __shared__ unsigned short Bl[96 * 192];   // 36864 B swizzled [n][k]
    __shared__ unsigned short Al[64 * 192];   // 24576 B swizzled [d][k]
    const int tid = threadIdx.x;
    const int b = blockIdx.y;
    const int nt0 = blockIdx.x * 96;
    const bool tail = (nt0 + 96 > NT);

    // stage A (already a swizzled image -> straight 16B copy)
    for (int i = tid; i < 1536; i += 256)
        *(short8*)((char*)Al + i * 16) = *(const short8*)((const char*)wswz + i * 16);

    // stage B: rows 0..63 from x (fp32 -> bf16), rows 64..191 from Y/Z (bf16)
    for (int i = tid; i < 768; i += 256) {
        int r = i / 12, ch = i - r * 12;
        int nt = nt0 + ch * 8;
        const float* sp = x + ((size_t)b * 64 + r) * NT + nt;
        float f[8];
        if (!tail || nt + 8 <= NT) {
            float4 v0 = *(const float4*)sp;
            float4 v1 = *(const float4*)(sp + 4);
            f[0] = v0.x; f[1] = v0.y; f[2] = v0.z; f[3] = v0.w;
            f[4] = v1.x; f[5] = v1.y; f[6] = v1.z; f[7] = v1.w;
        } else {
            #pragma unroll
            for (int jj = 0; jj < 8; ++jj) f[jj] = (nt + jj < NT) ? sp[jj] : 0.f;
        }
        int k2 = 2 * r;
        #pragma unroll
        for (int jj = 0; jj < 8; ++jj) {
            int n = ch * 8 + jj;
            *(unsigned short*)((char*)Bl + n * 384 + (k2 ^ swz(n))) = f2bf(f[jj]);
        }
    }
    for (int i = tid; i < 1536; i += 256) {
        int r = 64 + i / 12, ch = i % 12;
        int nt = nt0 + ch * 8;
        const unsigned short* base = (r < 128) ? Yg : Zg;
        const unsigned short* sp = base + ((size_t)b * 64 + (r & 63)) * NT + nt;
        unsigned short f[8];
        if (!tail || nt + 8 <= NT) {
            ushort4 v0 = *(const ushort4*)sp;
            ushort4 v1 = *(const ushort4*)(sp + 4);
            f[0] = v0.x; f[1] = v0.y; f[2] = v0.z; f[3] = v0.w;
            f[4] = v1.x; f[5] = v1.y; f[6] = v1.z; f[7] = v1.w;
        } else {
            #pragma unroll
            for (int jj = 0; jj < 8; ++jj) f[jj] = (nt + jj < NT) ? sp[jj] : (unsigned short)0;
        }
        int k2 = 2 * r;
        #pragma unroll
        for (int jj = 0; jj < 8; ++jj) {
            int n = ch * 8 + jj;
            *(unsigned short*)((char*)Bl + n * 384 + (k2 ^ swz(n))) = f[jj];
        }
    }
    __syncthreads();

    const int w = __builtin_amdgcn_readfirstlane(tid >> 6);
    const int l = tid & 63;
    const int lm = l & 15, lg = l >> 4;

    floatx4 acc[6];
    #pragma unroll
    for (int i = 0; i < 6; ++i) acc[i] = (floatx4){0.f, 0.f, 0.f, 0.f};

    const int arow = w * 16 + lm;
    const char* Ab = (const char*)Al + arow * 384;
    #pragma unroll
    for (int ks = 0; ks < 6; ++ks) {
        const int k2 = (ks * 32 + lg * 8) * 2;
        short8 a = *(const short8*)(Ab + (k2 ^ swz(arow)));
        #pragma unroll
        for (int ni = 0; ni < 6; ++ni) {
            int n = ni * 16 + lm;
            short8 bb = *(const short8*)((const char*)Bl + n * 384 + (k2 ^ swz(n)));
            acc[ni] = __builtin_amdgcn_mfma_f32_16x16x32_bf16(a, bb, acc[ni], 0, 0, 0);
        }
    }

    float br[4];
    #pragma unroll
    for (int j = 0; j < 4; ++j) br[j] = bias[w * 16 + lg * 4 + j];
    #pragma unroll
    for (int ni = 0; ni < 6; ++ni) {
        int nt = nt0 + ni * 16 + lm;
        if (nt < NT) {
            float* op = out + ((size_t)b * 64 + w * 16 + lg * 4) * NT + nt;
            #pragma unroll
            for (int j = 0; j < 4; ++j) op[(size_t)j * NT] = acc[ni][j] + br[j];
        }
    }
}

extern "C" void kernel_launch(void* const* d_in, const int* in_sizes, int n_in,
                              void* d_out, int out_size, void* d_ws, size_t ws_size,
                              hipStream_t stream) {
    const float* x   = (const float*)d_in[0];
    const float* adj = (const float*)d_in[1];
    const float* W   = (const float*)d_in[2];
    const float* b   = (const float*)d_in[3];
    float* out = (float*)d_out;

    char* ws = (char*)d_ws;
    // layout (bytes):
    //   0        : rowptr (326 i32 = 1304, pad 1312)
    //   1312     : edges  (<=105625 int2 = 845000, pad to 846320)
    //   846320   : wswz   (12288 bf16 = 24576)
    //   870896   : Y      (15974400 bf16 = 31948800)
    //   32819696 : Z      (15974400 bf16 = 31948800) -> end 64768496 (~61.8 MiB)
    int*   rowptr        = (int*)  (ws + 0);
    int2*  edges         = (int2*) (ws + 1312);
    unsigned short* wswz = (unsigned short*)(ws + 846320);
    unsigned short* Yg   = (unsigned short*)(ws + 870896);
    unsigned short* Zg   = (unsigned short*)(ws + 32819696);

    build_csr<<<1, 512, 0, stream>>>(adj, rowptr, edges);
    build_wswz<<<48, 256, 0, stream>>>(W, wswz);
    spmm16<0><<<256, 512, 0, stream>>>(x,  rowptr, edges, Yg);
    spmm16<1><<<256, 512, 0, stream>>>(Yg, rowptr, edges, Zg);
    mix_mfma<<<dim3(41, BATCH), 256, 0, stream>>>(x, Yg, Zg, wswz, b, out);
}

// Round 3
// 158.326 us; speedup vs baseline: 4.4126x; 2.8221x over previous
//
#include <hip/hip_runtime.h>
#include <hip/hip_bf16.h>

#define NND   325
#define SEQ   12
#define NT    3900            // 325*12
#define NPAD  336             // padded node rows in L image (21*16)
#define KP    352             // padded K for X/Y images (44 units of 8)
#define WROW  384             // Lg row width in shorts (48 units, all swizzled)
#define MB    48              // gt-rows per cheb block (4 g-slices)
#define NTILES 21             // 336/16

typedef __attribute__((ext_vector_type(8))) short short8;
typedef __attribute__((ext_vector_type(4))) float floatx4;
typedef __attribute__((ext_vector_type(4))) int intx4;

static __device__ __forceinline__ unsigned short f2bf(float f) {
    unsigned int u = __float_as_uint(f);
    unsigned int r = (u + 0x7fffu + ((u >> 16) & 1u)) >> 16;  // RNE
    return (unsigned short)r;
}
static __device__ __forceinline__ float bf2f(unsigned short u) {
    return __uint_as_float(((unsigned int)u) << 16);
}

// swizzle for mix kernel images (row stride 384 B) — unchanged from round 2
static __device__ __forceinline__ int swz(int n) {
    return ((n & 7) ^ ((n >> 3) & 7)) << 4;
}

// X/Y image index (shorts): row m (stride KP), col k. Units of 8 shorts,
// XOR within 128B groups; partial last group (units 40..43) unswizzled.
static __device__ __forceinline__ int xyidx(int m, int k) {
    int u = k >> 3;
    int uu = (u < 40) ? ((u & ~7) | ((u & 7) ^ (m & 7))) : u;
    return m * KP + uu * 8 + (k & 7);
}

// ---- setup: d^{-1/2} ----
__global__ void calc_dis(const float* __restrict__ adj, float* __restrict__ dis) {
    int i = blockIdx.x;
    const float* row = adj + (size_t)i * NND;
    float s = 0.f;
    for (int j = threadIdx.x; j < NND; j += 64) s += row[j];
    for (int o = 32; o; o >>= 1) s += __shfl_down(s, o);
    if (threadIdx.x == 0) dis[i] = (s > 0.f) ? rsqrtf(s) : 0.f;
}

// ---- setup: Lg[n][j] bf16, pre-swizzled within 128B groups, zero-padded ----
__global__ void build_L(const float* __restrict__ adj, const float* __restrict__ dis,
                        unsigned short* __restrict__ Lg) {
    int s = blockIdx.x * 256 + threadIdx.x;
    if (s >= NPAD * WROW) return;
    int n = s / WROW, w = s - n * WROW;
    int up = w >> 3, e = w & 7;
    int u = (up & ~7) | ((up & 7) ^ (n & 7));   // inverse (XOR self-inverse)
    int j = u * 8 + e;
    float v = 0.f;
    if (n < NND && j < NND) {
        float a = adj[(size_t)n * NND + j];
        v = ((n == j) ? 1.f : 0.f) - dis[n] * a * dis[j];
    }
    Lg[s] = f2bf(v);
}

// ---- setup: folded weights as swizzled bf16 image A[d][k], k=kind*64+c ----
__global__ void build_wswz(const float* __restrict__ W, unsigned short* __restrict__ wswz) {
    int idx = blockIdx.x * 256 + threadIdx.x;
    if (idx >= 64 * 192) return;
    int d = idx / 192, k = idx - d * 192;
    int kind = k >> 6, c = k & 63;
    float wv = W[kind * 4096 + c * 64 + d];
    float w;
    if (kind == 0)      w = wv - W[2 * 4096 + c * 64 + d];
    else if (kind == 1) w = wv;
    else                w = 2.f * wv;
    int byte = d * 384 + ((2 * k) ^ swz(d));
    wswz[byte >> 1] = f2bf(w);
}

// ---- Chebyshev double L-apply as dense MFMA GEMMs.
// Block: 48 gt-rows (4 g-slices). Y = X*L (K=352 padded), Z = Y*L. L symmetric:
// B-frags read from Lt[n][j-chunk]. Writes Y,Z to global [g][nt] bf16.
__global__ __launch_bounds__(512) void cheb_mfma(
        const float* __restrict__ x,
        const unsigned short* __restrict__ Lg,
        unsigned short* __restrict__ Yg,
        unsigned short* __restrict__ Zg) {
    __shared__ __align__(16) unsigned short Xs[MB * KP];        // 33792 B
    __shared__ __align__(16) unsigned short Ys[MB * KP];        // 33792 B
    __shared__ __align__(16) unsigned short Lt[2][NPAD * 64];   // 2 x 43008 B

    const int tid = threadIdx.x;
    int bid = blockIdx.x;
    bid = (bid & 7) * 128 + (bid >> 3);   // XCD swizzle (1024 = 8*128)
    const int g0 = bid * 4;

    const int w  = tid >> 6;
    const int l  = tid & 63;
    const int lm = l & 15, lg = l >> 4;
    const int s7 = lm & 7;

    intx4 st[6];
    auto loadL = [&](int c) {
        #pragma unroll
        for (int i = 0; i < 6; ++i) {
            int idx = tid + i * 512;
            if (idx < 2688) {
                int n = idx >> 3, p = idx & 7;
                st[i] = *(const intx4*)((const char*)Lg + (size_t)n * 768 + c * 128 + p * 16);
            }
        }
    };
    auto writeL = [&](unsigned short* buf) {
        #pragma unroll
        for (int i = 0; i < 6; ++i) {
            int idx = tid + i * 512;
            if (idx < 2688) *(intx4*)((char*)buf + idx * 16) = st[i];
        }
    };

    // zero pad columns (disjoint from staged region -> no barrier needed)
    for (int i = tid; i < MB * 27; i += 512) {      // Xs cols 325..351
        int m = i / 27, k = 325 + i - (i / 27) * 27;
        Xs[xyidx(m, k)] = 0;
    }
    for (int i = tid; i < MB * 16; i += 512) {      // Ys cols 336..351
        int m = i / 16, k = 336 + (i & 15);
        Ys[xyidx(m, k)] = 0;
    }

    loadL(0);   // L tile 0 in flight while we stage X

    // stage X: 3900 coalesced float4 -> bf16 swizzled image [m=gl*12+t][k=j]
    const float* xb = x + (size_t)g0 * NT;
    for (int i = tid; i < 3900; i += 512) {
        float4 v = ((const float4*)xb)[i];
        int f = i * 4;
        int gl = f / NT;
        int rem = f - gl * NT;
        int j = rem / SEQ;
        int t0 = rem - j * SEQ;          // 0,4,8
        int mb = gl * SEQ + t0;
        Xs[xyidx(mb + 0, j)] = f2bf(v.x);
        Xs[xyidx(mb + 1, j)] = f2bf(v.y);
        Xs[xyidx(mb + 2, j)] = f2bf(v.z);
        Xs[xyidx(mb + 3, j)] = f2bf(v.w);
    }
    writeL(Lt[0]);
    __syncthreads();

    floatx4 acc[3][3];
    auto zero_acc = [&]() {
        #pragma unroll
        for (int a = 0; a < 3; ++a)
            #pragma unroll
            for (int b2 = 0; b2 < 3; ++b2) acc[a][b2] = (floatx4){0.f, 0.f, 0.f, 0.f};
    };

    auto gemm_loop = [&](const unsigned short* Aimg) {
        for (int c = 0; c < 6; ++c) {
            if (c < 5) loadL(c + 1);
            const unsigned short* Lb = Lt[c & 1];
            #pragma unroll
            for (int h = 0; h < 2; ++h) {
                int ks = c * 2 + h;
                if (ks < 11) {
                    short8 af[3];
                    #pragma unroll
                    for (int mt = 0; mt < 3; ++mt) {
                        int m = mt * 16 + lm;
                        int u = ks * 4 + lg;
                        int uu = (u < 40) ? ((u & ~7) | ((u & 7) ^ s7)) : u;
                        af[mt] = *(const short8*)((const char*)Aimg + m * 704 + uu * 16);
                    }
                    int ul = (ks & 1) * 4 + lg;
                    #pragma unroll
                    for (int bi = 0; bi < 3; ++bi) {
                        int ti = w + 8 * bi;
                        if (ti < NTILES) {
                            int n = ti * 16 + lm;
                            short8 bf = *(const short8*)((const char*)Lb + n * 128 + (ul ^ s7) * 16);
                            #pragma unroll
                            for (int mt = 0; mt < 3; ++mt)
                                acc[mt][bi] = __builtin_amdgcn_mfma_f32_16x16x32_bf16(
                                    af[mt], bf, acc[mt][bi], 0, 0, 0);
                        }
                    }
                }
            }
            if (c < 5) writeL(Lt[(c + 1) & 1]);
            __syncthreads();
        }
    };

    auto store_acc = [&](unsigned short* img) {
        #pragma unroll
        for (int bi = 0; bi < 3; ++bi) {
            int ti = w + 8 * bi;
            if (ti < NTILES) {
                int n = ti * 16 + lm;
                #pragma unroll
                for (int mt = 0; mt < 3; ++mt)
                    #pragma unroll
                    for (int r = 0; r < 4; ++r)
                        img[xyidx(mt * 16 + lg * 4 + r, n)] = f2bf(acc[mt][bi][r]);
            }
        }
    };

    auto global_copy = [&](const unsigned short* img, unsigned short* dst) {
        for (int i = tid; i < 4 * NT; i += 512) {
            int gl = i / NT;
            int rem = i - gl * NT;
            int n = rem / SEQ, t = rem - n * SEQ;
            dst[(size_t)(g0 + gl) * NT + rem] = img[xyidx(gl * SEQ + t, n)];
        }
    };

    // ---- GEMM1: Y = X * L ----
    zero_acc();
    gemm_loop(Xs);
    store_acc(Ys);
    loadL(0);                 // prefetch tile 0 for GEMM2
    __syncthreads();          // Ys complete
    global_copy(Ys, Yg);
    writeL(Lt[0]);
    __syncthreads();

    // ---- GEMM2: Z = Y * L ----
    zero_acc();
    gemm_loop(Ys);
    store_acc(Xs);            // reuse Xs as Z staging
    __syncthreads();
    global_copy(Xs, Zg);
}

// ---- Phase B: out = A(64x192) x B(192 x 96nt) per (b, nt-tile), MFMA ----
__global__ __launch_bounds__(256) void mix_mfma(
        const float* __restrict__ x,
        const unsigned short* __restrict__ Yg,
        const unsigned short* __restrict__ Zg,
        const unsigned short* __restrict__ wswz,
        const float* __restrict__ bias,
        float* __restrict__ out) {
    __shared__ unsigned short Bl[96 * 192];   // 36864 B swizzled [n][k]
    __shared__ unsigned short Al[64 * 192];   // 24576 B swizzled [d][k]
    const int tid = threadIdx.x;
    int lin = blockIdx.x;
    lin = (lin & 7) * 328 + (lin >> 3);       // XCD swizzle (2624 = 8*328)
    const int b = lin / 41;
    const int nt0 = (lin - b * 41) * 96;
    const bool tail = (nt0 + 96 > NT);

    for (int i = tid; i < 1536; i += 256)
        *(short8*)((char*)Al + i * 16) = *(const short8*)((const char*)wswz + i * 16);

    for (int i = tid; i < 768; i += 256) {
        int r = i / 12, ch = i - r * 12;
        int nt = nt0 + ch * 8;
        const float* sp = x + ((size_t)b * 64 + r) * NT + nt;
        float f[8];
        if (!tail || nt + 8 <= NT) {
            float4 v0 = *(const float4*)sp;
            float4 v1 = *(const float4*)(sp + 4);
            f[0] = v0.x; f[1] = v0.y; f[2] = v0.z; f[3] = v0.w;
            f[4] = v1.x; f[5] = v1.y; f[6] = v1.z; f[7] = v1.w;
        } else {
            #pragma unroll
            for (int jj = 0; jj < 8; ++jj) f[jj] = (nt + jj < NT) ? sp[jj] : 0.f;
        }
        int k2 = 2 * r;
        #pragma unroll
        for (int jj = 0; jj < 8; ++jj) {
            int n = ch * 8 + jj;
            *(unsigned short*)((char*)Bl + n * 384 + (k2 ^ swz(n))) = f2bf(f[jj]);
        }
    }
    for (int i = tid; i < 1536; i += 256) {
        int r = 64 + i / 12, ch = i % 12;
        int nt = nt0 + ch * 8;
        const unsigned short* base = (r < 128) ? Yg : Zg;
        const unsigned short* sp = base + ((size_t)b * 64 + (r & 63)) * NT + nt;
        unsigned short f[8];
        if (!tail || nt + 8 <= NT) {
            ushort4 v0 = *(const ushort4*)sp;
            ushort4 v1 = *(const ushort4*)(sp + 4);
            f[0] = v0.x; f[1] = v0.y; f[2] = v0.z; f[3] = v0.w;
            f[4] = v1.x; f[5] = v1.y; f[6] = v1.z; f[7] = v1.w;
        } else {
            #pragma unroll
            for (int jj = 0; jj < 8; ++jj) f[jj] = (nt + jj < NT) ? sp[jj] : (unsigned short)0;
        }
        int k2 = 2 * r;
        #pragma unroll
        for (int jj = 0; jj < 8; ++jj) {
            int n = ch * 8 + jj;
            *(unsigned short*)((char*)Bl + n * 384 + (k2 ^ swz(n))) = f[jj];
        }
    }
    __syncthreads();

    const int w = __builtin_amdgcn_readfirstlane(tid >> 6);
    const int l = tid & 63;
    const int lm = l & 15, lg = l >> 4;

    floatx4 acc[6];
    #pragma unroll
    for (int i = 0; i < 6; ++i) acc[i] = (floatx4){0.f, 0.f, 0.f, 0.f};

    const int arow = w * 16 + lm;
    const char* Ab = (const char*)Al + arow * 384;
    #pragma unroll
    for (int ks = 0; ks < 6; ++ks) {
        const int k2 = (ks * 32 + lg * 8) * 2;
        short8 a = *(const short8*)(Ab + (k2 ^ swz(arow)));
        #pragma unroll
        for (int ni = 0; ni < 6; ++ni) {
            int n = ni * 16 + lm;
            short8 bb = *(const short8*)((const char*)Bl + n * 384 + (k2 ^ swz(n)));
            acc[ni] = __builtin_amdgcn_mfma_f32_16x16x32_bf16(a, bb, acc[ni], 0, 0, 0);
        }
    }

    float br[4];
    #pragma unroll
    for (int j = 0; j < 4; ++j) br[j] = bias[w * 16 + lg * 4 + j];
    #pragma unroll
    for (int ni = 0; ni < 6; ++ni) {
        int nt = nt0 + ni * 16 + lm;
        if (nt < NT) {
            float* op = out + ((size_t)b * 64 + w * 16 + lg * 4) * NT + nt;
            #pragma unroll
            for (int j = 0; j < 4; ++j) op[(size_t)j * NT] = acc[ni][j] + br[j];
        }
    }
}

extern "C" void kernel_launch(void* const* d_in, const int* in_sizes, int n_in,
                              void* d_out, int out_size, void* d_ws, size_t ws_size,
                              hipStream_t stream) {
    const float* x   = (const float*)d_in[0];
    const float* adj = (const float*)d_in[1];
    const float* W   = (const float*)d_in[2];
    const float* b   = (const float*)d_in[3];
    float* out = (float*)d_out;

    char* ws = (char*)d_ws;
    // layout (bytes):
    //   0        : dis   (325 f32, pad 1312)
    //   1312     : Lg    (336*384 bf16 = 258048)
    //   259584   : wswz  (12288 bf16 = 24576)
    //   284160   : Y     (4096*3900 bf16 = 31948800)
    //   32232960 : Z     (31948800) -> end 64181760 (~61.2 MiB)
    float* dis           = (float*)(ws + 0);
    unsigned short* Lg   = (unsigned short*)(ws + 1312);
    unsigned short* wswz = (unsigned short*)(ws + 259584);
    unsigned short* Yg   = (unsigned short*)(ws + 284160);
    unsigned short* Zg   = (unsigned short*)(ws + 32232960);

    calc_dis<<<NND, 64, 0, stream>>>(adj, dis);
    build_L<<<(NPAD * WROW + 255) / 256, 256, 0, stream>>>(adj, dis, Lg);
    build_wswz<<<48, 256, 0, stream>>>(W, wswz);
    cheb_mfma<<<1024, 512, 0, stream>>>(x, Lg, Yg, Zg);
    mix_mfma<<<2624, 256, 0, stream>>>(x, Yg, Zg, wswz, b, out);
}